// Round 11
// baseline (261.536 us; speedup 1.0000x reference)
//
#include <hip/hip_runtime.h>
#include <hip/hip_cooperative_groups.h>
#include <math.h>

namespace cg = cooperative_groups;

#define N_NODES 50000
#define N_EDGES 600000
#define DIM 128
#define HEADS 8
#define GBLK 1563   // (N_NODES+31)/32
#define NB1 586     // L1 sort blocks, 1024 edges each
#define L1E 1024

typedef _Float16 v8h __attribute__((ext_vector_type(8)));
typedef _Float16 v2h __attribute__((ext_vector_type(2)));
typedef float v16f __attribute__((ext_vector_type(16)));
typedef float v2f __attribute__((ext_vector_type(2)));

union v8h_u {
    v8h v;
    v2h p[4];
    _Float16 e[8];
};

// ---------------- fp8 e4m3 helpers (gfx950 HW cvt; OCP e4m3fn) ----------------
__device__ __forceinline__ float e4m3_to_f32_sw(unsigned int b) {
    unsigned int s = b >> 7, E = (b >> 3) & 0xF, m = b & 7;
    float v = (E == 0) ? (float)m * 0.001953125f
                       : ldexpf(1.0f + (float)m * 0.125f, (int)E - 7);
    return s ? -v : v;
}

template <bool HI>
__device__ __forceinline__ v2f cvt2_f8(unsigned int w) {
#if __has_builtin(__builtin_amdgcn_cvt_pk_f32_fp8)
    return __builtin_amdgcn_cvt_pk_f32_fp8((int)w, HI);
#else
    v2f r;
    r[0] = e4m3_to_f32_sw((w >> (HI ? 16 : 0)) & 0xff);
    r[1] = e4m3_to_f32_sw((w >> (HI ? 24 : 8)) & 0xff);
    return r;
#endif
}

__device__ __forceinline__ unsigned char f32_to_e4m3(float v) {
#if __has_builtin(__builtin_amdgcn_cvt_pk_fp8_f32)
    return (unsigned char)(__builtin_amdgcn_cvt_pk_fp8_f32(v, v, 0, false) & 0xff);
#else
    float a = fabsf(v);
    unsigned char sgn = (v < 0.f) ? 0x80 : 0;
    if (!(a >= 0.0078125f)) {
        int m = (int)(a * 512.0f + 0.5f);
        if (m > 7) return sgn | 8;
        return sgn | (unsigned char)m;
    }
    if (a >= 448.0f) return sgn | 0x7e;
    int e;
    float fr = frexpf(a, &e);
    int mant = (int)(fr * 16.0f + 0.5f);
    int E = e + 6;
    if (mant == 16) { mant = 8; E++; }
    if (E >= 16) return sgn | 0x7e;
    return sgn | (unsigned char)((E << 3) | (mant - 8));
#endif
}

// ---------------- K1: W-frag transform + L1 coarse histogram (block-split) ------------
// blocks [0,64): Wfrag; blocks [64, 64+NB1): per-block LDS hist of digit (row>>8).
__global__ __launch_bounds__(256) void prep_hist(const float* __restrict__ Wq,
                                                 const float* __restrict__ Wk,
                                                 const float* __restrict__ Wv,
                                                 const float* __restrict__ Wo,
                                                 _Float16* __restrict__ Wfrag,
                                                 const int* __restrict__ rowi,
                                                 int* __restrict__ bh) {
    __shared__ int lh[256];
    if (blockIdx.x >= 64) {
        int b = blockIdx.x - 64;
        int t = threadIdx.x;
        lh[t] = 0;
        __syncthreads();
        int e0 = b * L1E + t;
#pragma unroll
        for (int k = 0; k < 4; k++) {
            int e = e0 + k * 256;
            if (e < N_EDGES) atomicAdd(lh + (rowi[e] >> 8), 1);
        }
        __syncthreads();
        bh[t * NB1 + b] = lh[t];
        return;
    }
    int i = blockIdx.x * 256 + threadIdx.x;  // < 16384
    int base = i * 4;
    int mat = i >> 12;
    int rem = i & 4095;
    int wave = rem >> 10;
    int kt = (rem >> 7) & 7;
    int lane = (rem >> 1) & 63;
    int jh = (rem & 1) * 4;
    const float* src = (mat == 0) ? Wq : (mat == 1) ? Wk : (mat == 2) ? Wv : Wo;
    int n = wave * 32 + (lane & 31);
    int kbase = kt * 16 + (lane >> 5) * 8 + jh;
    _Float16 o[4];
#pragma unroll
    for (int j = 0; j < 4; j++) o[j] = (_Float16)src[(kbase + j) * 128 + n];
    *(short4*)(Wfrag + base) = *(short4*)o;
}

// ---------------- K2: fused QKV GEMM + scanA (block-split) ----------------
// blocks [0, GBLK): QKV projection (Q,V f16; K fp8)
// blocks [GBLK, GBLK+256): per-digit exclusive scan over blocks + digit totals
#define LDSTRIDE 132
__global__ __launch_bounds__(256) void qkv_scan(const float* __restrict__ x,
                                                const _Float16* __restrict__ Wfrag,
                                                const float* __restrict__ bq,
                                                const float* __restrict__ bk,
                                                const float* __restrict__ bv,
                                                _Float16* __restrict__ Qh,
                                                unsigned char* __restrict__ K8,
                                                _Float16* __restrict__ Vh,
                                                const int* __restrict__ bh,
                                                int* __restrict__ within,
                                                int* __restrict__ dt) {
    __shared__ _Float16 As[32 * LDSTRIDE];
    __shared__ int sh[256];
    if (blockIdx.x >= GBLK) {
        int d = blockIdx.x - GBLK;  // digit 0..255
        int t = threadIdx.x;
        int carry = 0;
        for (int c = 0; c < 3; c++) {
            int j = c * 256 + t;
            int v = (j < NB1) ? bh[d * NB1 + j] : 0;
            __syncthreads();
            sh[t] = v;
            __syncthreads();
            for (int off = 1; off < 256; off <<= 1) {
                int a = sh[t];
                int b2 = (t >= off) ? sh[t - off] : 0;
                __syncthreads();
                sh[t] = a + b2;
                __syncthreads();
            }
            if (j < NB1) within[d * NB1 + j] = carry + sh[t] - v;
            carry += sh[255];
        }
        if (t == 0) dt[d] = carry;
        return;
    }
    int tid = threadIdx.x;
    int wave = tid >> 6, lane = tid & 63;
    int m32 = lane & 31, quad = lane >> 5;
    int row0 = blockIdx.x * 32;

    {
        int r = tid >> 3;
        int c0 = (tid & 7) * 16;
        int gr = row0 + r;
        bool valid = gr < N_NODES;
        const float4* src = (const float4*)(x + (size_t)gr * 128 + c0);
        _Float16* dst = As + r * LDSTRIDE + c0;
#pragma unroll
        for (int q = 0; q < 4; q++) {
            float4 v = valid ? src[q] : make_float4(0.f, 0.f, 0.f, 0.f);
            _Float16 o[4] = {(_Float16)v.x, (_Float16)v.y, (_Float16)v.z, (_Float16)v.w};
            *(short4*)(dst + q * 4) = *(short4*)o;
        }
    }
    __syncthreads();

    v8h af[8];
#pragma unroll
    for (int kt = 0; kt < 8; kt++)
        af[kt] = *(const v8h*)(As + m32 * LDSTRIDE + kt * 16 + quad * 8);

    int col = wave * 32 + m32;
#pragma unroll
    for (int mat = 0; mat < 3; mat++) {
        const _Float16* wf = Wfrag + mat * 16384 + wave * 4096 + lane * 8;
        v16f acc;
#pragma unroll
        for (int r = 0; r < 16; r++) acc[r] = 0.0f;
#pragma unroll
        for (int kt = 0; kt < 8; kt++) {
            v8h bf = *(const v8h*)(wf + kt * 512);
            acc = __builtin_amdgcn_mfma_f32_32x32x16_f16(af[kt], bf, acc, 0, 0, 0);
        }
        const float* bias = (mat == 0) ? bq : (mat == 1) ? bk : bv;
        float bias_v = bias[col];
        if (mat == 1) {
#pragma unroll
            for (int r = 0; r < 16; r++) {
                int row = (r & 3) + 8 * (r >> 2) + 4 * quad;
                int gr = row0 + row;
                if (gr < N_NODES) K8[(size_t)gr * 128 + col] = f32_to_e4m3(acc[r] + bias_v);
            }
        } else {
            _Float16* C = (mat == 0) ? Qh : Vh;
#pragma unroll
            for (int r = 0; r < 16; r++) {
                int row = (r & 3) + 8 * (r >> 2) + 4 * quad;
                int gr = row0 + row;
                if (gr < N_NODES) C[(size_t)gr * 128 + col] = (_Float16)(acc[r] + bias_v);
            }
        }
    }
}

// ---------------- K3 (cooperative): l1scat -> grid.sync -> l2sort ----------------
// Each block locally scans dt[256] (replaces scanB). Phase B: coarse scatter with
// LDS rank (rec1 = row | col<<16 | f16(eattr)<<32). Phase C (blocks<196): in-bucket
// sort -> ep4 + counts/start.
__global__ __launch_bounds__(256) void sortk(const int* __restrict__ rowi,
                                             const int* __restrict__ coli,
                                             const float* __restrict__ eattr,
                                             const int* __restrict__ within,
                                             const int* __restrict__ dt,
                                             unsigned long long* __restrict__ rec1,
                                             int* __restrict__ counts,
                                             int* __restrict__ start,
                                             unsigned int* __restrict__ ep4) {
    cg::grid_group grid = cg::this_grid();
    __shared__ int s0_[256], s1_[256], s2_[256], s3_[256];
    int b = blockIdx.x, t = threadIdx.x;

    // local exclusive scan of dt -> dto (s3_)
    int v = dt[t];
    s0_[t] = v;
    __syncthreads();
    for (int off = 1; off < 256; off <<= 1) {
        int a = s0_[t];
        int b2 = (t >= off) ? s0_[t - off] : 0;
        __syncthreads();
        s0_[t] = a + b2;
        __syncthreads();
    }
    s3_[t] = s0_[t] - v;  // dto[t]

    // ---- phase B: L1 coarse scatter ----
    s1_[t] = 0;                          // lh
    s2_[t] = s3_[t] + within[t * NB1 + b];  // base per digit
    __syncthreads();
    int e0 = b * L1E + t;
#pragma unroll
    for (int k = 0; k < 4; k++) {
        int e = e0 + k * 256;
        if (e < N_EDGES) {
            int row = rowi[e];
            int d = row >> 8;
            int r = atomicAdd(s1_ + d, 1);
            unsigned short eb = __builtin_bit_cast(unsigned short, (_Float16)eattr[e]);
            rec1[s2_[d] + r] = (unsigned long long)row |
                               ((unsigned long long)(unsigned int)coli[e] << 16) |
                               ((unsigned long long)eb << 32);
        }
    }

    grid.sync();

    // ---- phase C: in-bucket sort (blocks < 196) ----
    if (b < 196) {
        int d = b;
        int seg = s3_[d];  // dto[d] (uniform read)
        int cnt = dt[d];
        int e = seg + cnt;
        __syncthreads();  // all threads have read s3_/dt before LDS reuse
        s0_[t] = 0;       // h
        s2_[t] = 0;       // r2
        __syncthreads();
        for (int i = seg + t; i < e; i += 256) atomicAdd(s0_ + (int)(rec1[i] & 255), 1);
        __syncthreads();
        int hv = s0_[t];
        s3_[t] = hv;
        __syncthreads();
        for (int off = 1; off < 256; off <<= 1) {
            int a = s3_[t];
            int b2 = (t >= off) ? s3_[t - off] : 0;
            __syncthreads();
            s3_[t] = a + b2;
            __syncthreads();
        }
        int ex = s3_[t] - hv;
        s1_[t] = ex;  // hs
        int node = (d << 8) | t;
        if (node < N_NODES) {
            counts[node] = hv;
            start[node] = seg + ex;
        }
        __syncthreads();
        for (int i = seg + t; i < e; i += 256) {
            unsigned long long w = rec1[i];
            int ld = (int)(w & 255);
            int r = atomicAdd(s2_ + ld, 1);
            ep4[seg + s1_[ld] + r] = (unsigned int)(w >> 16);  // col | f16(eattr)<<16
        }
    }
}

// ---------------- output GEMM: LDS-staged f16 A, f32 out ----------------
__global__ __launch_bounds__(256) void gemm_out(const _Float16* __restrict__ Ah,
                                                const _Float16* __restrict__ Wfrag,
                                                const float* __restrict__ bo,
                                                float* __restrict__ C) {
    __shared__ _Float16 As[32 * LDSTRIDE];
    int tid = threadIdx.x;
    int wave = tid >> 6, lane = tid & 63;
    int m32 = lane & 31, quad = lane >> 5;
    int row0 = blockIdx.x * 32;

    {
        int r = tid >> 3;
        int c0 = (tid & 7) * 16;
        int gr = row0 + r;
        bool valid = gr < N_NODES;
        const v8h* src = (const v8h*)(Ah + (size_t)gr * 128 + c0);
        _Float16* dst = As + r * LDSTRIDE + c0;
        v8h z = {};
        *(v8h*)(dst) = valid ? src[0] : z;
        *(v8h*)(dst + 8) = valid ? src[1] : z;
    }
    __syncthreads();

    v8h af[8];
#pragma unroll
    for (int kt = 0; kt < 8; kt++)
        af[kt] = *(const v8h*)(As + m32 * LDSTRIDE + kt * 16 + quad * 8);

    int col = wave * 32 + m32;
    const _Float16* wf = Wfrag + 3 * 16384 + wave * 4096 + lane * 8;
    v16f acc;
#pragma unroll
    for (int r = 0; r < 16; r++) acc[r] = 0.0f;
#pragma unroll
    for (int kt = 0; kt < 8; kt++) {
        v8h bf = *(const v8h*)(wf + kt * 512);
        acc = __builtin_amdgcn_mfma_f32_32x32x16_f16(af[kt], bf, acc, 0, 0, 0);
    }
    float bias_v = bo[col];
#pragma unroll
    for (int r = 0; r < 16; r++) {
        int row = (r & 3) + 8 * (r >> 2) + 4 * quad;
        int gr = row0 + row;
        if (gr < N_NODES) C[(size_t)gr * 128 + col] = acc[r] + bias_v;
    }
}

// ---------------- fused attention: 16 lanes/node, K fp8 + V f16, 4B edge records ------
// R2 structure, K fp8 (R6: absmax 0.0098). no-max softmax (R1). Tail clamp to
// THIS node's last edge (e1-1). ep4: u16 col | f16 eattr.
__global__ __launch_bounds__(256) void fused_attn(const _Float16* __restrict__ Q,
                                                  const unsigned char* __restrict__ K8,
                                                  const _Float16* __restrict__ V,
                                                  const int* __restrict__ start,
                                                  const int* __restrict__ counts,
                                                  const unsigned int* __restrict__ ep4,
                                                  _Float16* __restrict__ Aout) {
    int t = blockIdx.x * 256 + threadIdx.x;
    int n = t >> 4;
    int sub = t & 15;
    if (n >= N_NODES) return;

    int s0 = start[n];
    int cnt = counts[n];
    int e1 = s0 + cnt;

    v8h_u q;
    q.v = *(const v8h*)(Q + (size_t)n * 128 + sub * 8);
    float qf[8];
#pragma unroll
    for (int j = 0; j < 8; j++) qf[j] = (float)q.e[j];

    const unsigned char* Kb = K8 + sub * 8;
    const _Float16* Vb = V + sub * 8;

    float l = 0.0f;
    float acc[8];
#pragma unroll
    for (int j = 0; j < 8; j++) acc[j] = 0.0f;

    int nb = (cnt + 15) >> 4;  // 16-edge super-blocks
    for (int b = 0; b < nb; b++) {
        int base = s0 + (b << 4);
        int li = base + sub;
        if (li >= e1) li = e1 - 1;
        unsigned int pv = ep4[li];

#pragma unroll
        for (int h = 0; h < 2; h++) {
            int hb = h << 3;
            if (base + hb < e1) {
                int cols[8];
                float eas[8];
#pragma unroll
                for (int u = 0; u < 8; u++) {
                    unsigned int w = (unsigned int)__shfl((int)pv, hb + u, 16);
                    cols[u] = (int)(w & 0xffffu);
                    eas[u] = (float)__builtin_bit_cast(_Float16, (unsigned short)(w >> 16));
                }
                // ---- load phase: 8x8B K + 8x16B V gathers, issued before any compute ----
                uint2 kw[8];
                v8h_u vv[8];
#pragma unroll
                for (int u = 0; u < 8; u++) {
                    kw[u] = *(const uint2*)(Kb + ((size_t)cols[u] << 7));
                    vv[u].v = *(const v8h*)(Vb + ((size_t)cols[u] << 7));
                }
                __builtin_amdgcn_sched_barrier(0);
                // ---- compute phase ----
#pragma unroll
                for (int u = 0; u < 8; u++) {
                    v2f k01 = cvt2_f8<false>(kw[u].x);
                    v2f k23 = cvt2_f8<true>(kw[u].x);
                    v2f k45 = cvt2_f8<false>(kw[u].y);
                    v2f k67 = cvt2_f8<true>(kw[u].y);
                    float dot = 0.0f;
                    dot = fmaf(qf[0], k01[0], dot);
                    dot = fmaf(qf[1], k01[1], dot);
                    dot = fmaf(qf[2], k23[0], dot);
                    dot = fmaf(qf[3], k23[1], dot);
                    dot = fmaf(qf[4], k45[0], dot);
                    dot = fmaf(qf[5], k45[1], dot);
                    dot = fmaf(qf[6], k67[0], dot);
                    dot = fmaf(qf[7], k67[1], dot);
                    dot += __shfl_xor(dot, 1);  // 2 lanes per head
                    float s = dot * 0.25f + eas[u];
                    bool valid = (base + hb + u) < e1;
                    float ex = valid ? __expf(s) : 0.0f;
                    l += ex;
#pragma unroll
                    for (int j = 0; j < 8; j++) acc[j] = fmaf(ex, (float)vv[u].e[j], acc[j]);
                }
            }
        }
    }

    float inv = 1.0f / (l + 1e-8f);
    _Float16 tmp[8];
#pragma unroll
    for (int j = 0; j < 8; j++) tmp[j] = (_Float16)(acc[j] * inv);
    *(v8h*)(Aout + (size_t)n * 128 + sub * 8) = *(v8h*)tmp;
}

extern "C" void kernel_launch(void* const* d_in, const int* in_sizes, int n_in,
                              void* d_out, int out_size, void* d_ws, size_t ws_size,
                              hipStream_t stream) {
    const float* x = (const float*)d_in[0];
    const int* ei = (const int*)d_in[1];
    const float* eattr = (const float*)d_in[2];
    const float* Wq = (const float*)d_in[3];
    const float* bq = (const float*)d_in[4];
    const float* Wk = (const float*)d_in[5];
    const float* bk = (const float*)d_in[6];
    const float* Wv = (const float*)d_in[7];
    const float* bv = (const float*)d_in[8];
    const float* Wo = (const float*)d_in[9];
    const float* bo = (const float*)d_in[10];
    float* out = (float*)d_out;

    const int* rowi = ei;
    const int* coli = ei + N_EDGES;

    // workspace carve (rec1 offset 8B-aligned by construction)
    _Float16* Qh = (_Float16*)d_ws;
    _Float16* Vh = Qh + (size_t)N_NODES * DIM;
    _Float16* Ah = Vh + (size_t)N_NODES * DIM;
    unsigned char* K8 = (unsigned char*)(Ah + (size_t)N_NODES * DIM);
    _Float16* Wfrag = (_Float16*)(K8 + (size_t)N_NODES * DIM);  // 4*16384 shorts
    int* counts = (int*)(Wfrag + 4 * 16384);
    int* start = counts + N_NODES;
    int* bh = start + N_NODES;            // 256*NB1
    int* within = bh + 256 * NB1;         // 256*NB1
    int* dt = within + 256 * NB1;         // 256 (+pad to 8B)
    unsigned long long* rec1 = (unsigned long long*)(dt + 256);  // N_EDGES u64
    unsigned int* ep4 = (unsigned int*)(rec1 + N_EDGES);

    // 1. W frag transform || L1 coarse hist
    prep_hist<<<64 + NB1, 256, 0, stream>>>(Wq, Wk, Wv, Wo, Wfrag, rowi, bh);
    // 2. QKV projection || scanA (within-digit over blocks; digit totals)
    qkv_scan<<<GBLK + 256, 256, 0, stream>>>(x, Wfrag, bq, bk, bv, Qh, K8, Vh,
                                             bh, within, dt);
    // 3. cooperative: L1 scatter -> grid sync -> L2 in-bucket sort
    {
        void* rowi_p = (void*)rowi;
        void* coli_p = (void*)coli;
        void* eattr_p = (void*)eattr;
        void* within_p = (void*)within;
        void* dt_p = (void*)dt;
        void* rec1_p = (void*)rec1;
        void* counts_p = (void*)counts;
        void* start_p = (void*)start;
        void* ep4_p = (void*)ep4;
        void* args[] = {&rowi_p, &coli_p, &eattr_p, &within_p, &dt_p,
                        &rec1_p, &counts_p, &start_p, &ep4_p};
        hipLaunchCooperativeKernel((void*)sortk, dim3(NB1), dim3(256), args, 0, stream);
    }
    // 4. fused gather-attention (16 lanes per node, K fp8 + V f16)
    int ablocks = (N_NODES * 16 + 255) / 256;
    fused_attn<<<ablocks, 256, 0, stream>>>(Qh, K8, Vh, start, counts, ep4, Ah);
    // 5. output projection
    gemm_out<<<GBLK, 256, 0, stream>>>(Ah, Wfrag, bo, out);
}

// Round 12
// 177.678 us; speedup vs baseline: 1.4720x; 1.4720x over previous
//
#include <hip/hip_runtime.h>
#include <math.h>

#define N_NODES 50000
#define N_EDGES 600000
#define DIM 128
#define HEADS 8
#define GBLK 1563   // (N_NODES+31)/32
#define NB1 586     // L1 sort blocks, 1024 edges each
#define L1E 1024

typedef _Float16 v8h __attribute__((ext_vector_type(8)));
typedef _Float16 v2h __attribute__((ext_vector_type(2)));
typedef float v16f __attribute__((ext_vector_type(16)));
typedef float v2f __attribute__((ext_vector_type(2)));

union v8h_u {
    v8h v;
    v2h p[4];
    _Float16 e[8];
};

// ---------------- fp8 e4m3 helpers (gfx950 HW cvt; OCP e4m3fn) ----------------
__device__ __forceinline__ float e4m3_to_f32_sw(unsigned int b) {
    unsigned int s = b >> 7, E = (b >> 3) & 0xF, m = b & 7;
    float v = (E == 0) ? (float)m * 0.001953125f
                       : ldexpf(1.0f + (float)m * 0.125f, (int)E - 7);
    return s ? -v : v;
}

template <bool HI>
__device__ __forceinline__ v2f cvt2_f8(unsigned int w) {
#if __has_builtin(__builtin_amdgcn_cvt_pk_f32_fp8)
    return __builtin_amdgcn_cvt_pk_f32_fp8((int)w, HI);
#else
    v2f r;
    r[0] = e4m3_to_f32_sw((w >> (HI ? 16 : 0)) & 0xff);
    r[1] = e4m3_to_f32_sw((w >> (HI ? 24 : 8)) & 0xff);
    return r;
#endif
}

__device__ __forceinline__ unsigned char f32_to_e4m3(float v) {
#if __has_builtin(__builtin_amdgcn_cvt_pk_fp8_f32)
    return (unsigned char)(__builtin_amdgcn_cvt_pk_fp8_f32(v, v, 0, false) & 0xff);
#else
    float a = fabsf(v);
    unsigned char sgn = (v < 0.f) ? 0x80 : 0;
    if (!(a >= 0.0078125f)) {
        int m = (int)(a * 512.0f + 0.5f);
        if (m > 7) return sgn | 8;
        return sgn | (unsigned char)m;
    }
    if (a >= 448.0f) return sgn | 0x7e;
    int e;
    float fr = frexpf(a, &e);
    int mant = (int)(fr * 16.0f + 0.5f);
    int E = e + 6;
    if (mant == 16) { mant = 8; E++; }
    if (E >= 16) return sgn | 0x7e;
    return sgn | (unsigned char)((E << 3) | (mant - 8));
#endif
}

// ---------------- K1: W-frag transform + L1 coarse histogram (block-split) ------------
// blocks [0,64): Wfrag; blocks [64, 64+NB1): per-block LDS hist of digit (row>>8).
__global__ __launch_bounds__(256) void prep_hist(const float* __restrict__ Wq,
                                                 const float* __restrict__ Wk,
                                                 const float* __restrict__ Wv,
                                                 const float* __restrict__ Wo,
                                                 _Float16* __restrict__ Wfrag,
                                                 const int* __restrict__ rowi,
                                                 int* __restrict__ bh) {
    __shared__ int lh[256];
    if (blockIdx.x >= 64) {
        int b = blockIdx.x - 64;
        int t = threadIdx.x;
        lh[t] = 0;
        __syncthreads();
        int e0 = b * L1E + t;
#pragma unroll
        for (int k = 0; k < 4; k++) {
            int e = e0 + k * 256;
            if (e < N_EDGES) atomicAdd(lh + (rowi[e] >> 8), 1);
        }
        __syncthreads();
        bh[t * NB1 + b] = lh[t];
        return;
    }
    int i = blockIdx.x * 256 + threadIdx.x;  // < 16384
    int base = i * 4;
    int mat = i >> 12;
    int rem = i & 4095;
    int wave = rem >> 10;
    int kt = (rem >> 7) & 7;
    int lane = (rem >> 1) & 63;
    int jh = (rem & 1) * 4;
    const float* src = (mat == 0) ? Wq : (mat == 1) ? Wk : (mat == 2) ? Wv : Wo;
    int n = wave * 32 + (lane & 31);
    int kbase = kt * 16 + (lane >> 5) * 8 + jh;
    _Float16 o[4];
#pragma unroll
    for (int j = 0; j < 4; j++) o[j] = (_Float16)src[(kbase + j) * 128 + n];
    *(short4*)(Wfrag + base) = *(short4*)o;
}

// ---------------- K2: fused QKV GEMM + scanA (block-split) ----------------
// blocks [0, GBLK): QKV projection (Q,V f16; K fp8)
// blocks [GBLK, GBLK+256): per-digit exclusive scan over blocks + digit totals
#define LDSTRIDE 132
__global__ __launch_bounds__(256) void qkv_scan(const float* __restrict__ x,
                                                const _Float16* __restrict__ Wfrag,
                                                const float* __restrict__ bq,
                                                const float* __restrict__ bk,
                                                const float* __restrict__ bv,
                                                _Float16* __restrict__ Qh,
                                                unsigned char* __restrict__ K8,
                                                _Float16* __restrict__ Vh,
                                                const int* __restrict__ bh,
                                                int* __restrict__ within,
                                                int* __restrict__ dt) {
    __shared__ _Float16 As[32 * LDSTRIDE];
    __shared__ int sh[256];
    if (blockIdx.x >= GBLK) {
        int d = blockIdx.x - GBLK;  // digit 0..255
        int t = threadIdx.x;
        int carry = 0;
        for (int c = 0; c < 3; c++) {
            int j = c * 256 + t;
            int v = (j < NB1) ? bh[d * NB1 + j] : 0;
            __syncthreads();
            sh[t] = v;
            __syncthreads();
            for (int off = 1; off < 256; off <<= 1) {
                int a = sh[t];
                int b2 = (t >= off) ? sh[t - off] : 0;
                __syncthreads();
                sh[t] = a + b2;
                __syncthreads();
            }
            if (j < NB1) within[d * NB1 + j] = carry + sh[t] - v;
            carry += sh[255];
        }
        if (t == 0) dt[d] = carry;
        return;
    }
    int tid = threadIdx.x;
    int wave = tid >> 6, lane = tid & 63;
    int m32 = lane & 31, quad = lane >> 5;
    int row0 = blockIdx.x * 32;

    {
        int r = tid >> 3;
        int c0 = (tid & 7) * 16;
        int gr = row0 + r;
        bool valid = gr < N_NODES;
        const float4* src = (const float4*)(x + (size_t)gr * 128 + c0);
        _Float16* dst = As + r * LDSTRIDE + c0;
#pragma unroll
        for (int q = 0; q < 4; q++) {
            float4 v = valid ? src[q] : make_float4(0.f, 0.f, 0.f, 0.f);
            _Float16 o[4] = {(_Float16)v.x, (_Float16)v.y, (_Float16)v.z, (_Float16)v.w};
            *(short4*)(dst + q * 4) = *(short4*)o;
        }
    }
    __syncthreads();

    v8h af[8];
#pragma unroll
    for (int kt = 0; kt < 8; kt++)
        af[kt] = *(const v8h*)(As + m32 * LDSTRIDE + kt * 16 + quad * 8);

    int col = wave * 32 + m32;
#pragma unroll
    for (int mat = 0; mat < 3; mat++) {
        const _Float16* wf = Wfrag + mat * 16384 + wave * 4096 + lane * 8;
        v16f acc;
#pragma unroll
        for (int r = 0; r < 16; r++) acc[r] = 0.0f;
#pragma unroll
        for (int kt = 0; kt < 8; kt++) {
            v8h bf = *(const v8h*)(wf + kt * 512);
            acc = __builtin_amdgcn_mfma_f32_32x32x16_f16(af[kt], bf, acc, 0, 0, 0);
        }
        const float* bias = (mat == 0) ? bq : (mat == 1) ? bk : bv;
        float bias_v = bias[col];
        if (mat == 1) {
#pragma unroll
            for (int r = 0; r < 16; r++) {
                int row = (r & 3) + 8 * (r >> 2) + 4 * quad;
                int gr = row0 + row;
                if (gr < N_NODES) K8[(size_t)gr * 128 + col] = f32_to_e4m3(acc[r] + bias_v);
            }
        } else {
            _Float16* C = (mat == 0) ? Qh : Vh;
#pragma unroll
            for (int r = 0; r < 16; r++) {
                int row = (r & 3) + 8 * (r >> 2) + 4 * quad;
                int gr = row0 + row;
                if (gr < N_NODES) C[(size_t)gr * 128 + col] = (_Float16)(acc[r] + bias_v);
            }
        }
    }
}

// ---------------- K3: L1 coarse scatter (regular kernel; local dt scan) ----------
// rec1[pos] = row | col<<16 | f16(eattr)<<32. Kernel boundary (not grid.sync) is the
// cross-XCD visibility point — R11's cooperative fusion cost 80us in L2-flush/spin.
__global__ __launch_bounds__(256) void l1scat(const int* __restrict__ rowi,
                                              const int* __restrict__ coli,
                                              const float* __restrict__ eattr,
                                              const int* __restrict__ within,
                                              const int* __restrict__ dt,
                                              unsigned long long* __restrict__ rec1) {
    __shared__ int lh[256], base[256], sh[256];
    int b = blockIdx.x, t = threadIdx.x;
    // local exclusive scan of dt -> dto
    int v = dt[t];
    sh[t] = v;
    __syncthreads();
    for (int off = 1; off < 256; off <<= 1) {
        int a = sh[t];
        int b2 = (t >= off) ? sh[t - off] : 0;
        __syncthreads();
        sh[t] = a + b2;
        __syncthreads();
    }
    int dto = sh[t] - v;
    lh[t] = 0;
    base[t] = dto + within[t * NB1 + b];
    __syncthreads();
    int e0 = b * L1E + t;
#pragma unroll
    for (int k = 0; k < 4; k++) {
        int e = e0 + k * 256;
        if (e < N_EDGES) {
            int row = rowi[e];
            int d = row >> 8;
            int r = atomicAdd(lh + d, 1);
            unsigned short eb = __builtin_bit_cast(unsigned short, (_Float16)eattr[e]);
            rec1[base[d] + r] = (unsigned long long)row |
                                ((unsigned long long)(unsigned int)coli[e] << 16) |
                                ((unsigned long long)eb << 32);
        }
    }
}

// ---------------- K4: L2 in-bucket sort -> ep4 + counts/start (local dt scan) --------
__global__ __launch_bounds__(256) void l2sort(const unsigned long long* __restrict__ rec1,
                                              const int* __restrict__ dt,
                                              int* __restrict__ counts,
                                              int* __restrict__ start,
                                              unsigned int* __restrict__ ep4) {
    __shared__ int h[256], hs[256], r2[256], sh[256];
    int d = blockIdx.x, t = threadIdx.x;
    // local exclusive scan of dt -> seg = dto[d]
    int v0 = dt[t];
    sh[t] = v0;
    __syncthreads();
    for (int off = 1; off < 256; off <<= 1) {
        int a = sh[t];
        int b2 = (t >= off) ? sh[t - off] : 0;
        __syncthreads();
        sh[t] = a + b2;
        __syncthreads();
    }
    int cnt = dt[d];
    int s = sh[d] - cnt;  // dto[d]
    int e = s + cnt;
    __syncthreads();
    h[t] = 0;
    r2[t] = 0;
    __syncthreads();
    for (int i = s + t; i < e; i += 256) atomicAdd(h + (int)(rec1[i] & 255), 1);
    __syncthreads();
    int v = h[t];
    sh[t] = v;
    __syncthreads();
    for (int off = 1; off < 256; off <<= 1) {
        int a = sh[t];
        int b2 = (t >= off) ? sh[t - off] : 0;
        __syncthreads();
        sh[t] = a + b2;
        __syncthreads();
    }
    int ex = sh[t] - v;  // exclusive prefix within bucket
    hs[t] = ex;
    int node = (d << 8) | t;
    if (node < N_NODES) {
        counts[node] = v;
        start[node] = s + ex;
    }
    __syncthreads();
    for (int i = s + t; i < e; i += 256) {
        unsigned long long w = rec1[i];
        int ld = (int)(w & 255);
        int r = atomicAdd(r2 + ld, 1);
        ep4[s + hs[ld] + r] = (unsigned int)(w >> 16);  // col | f16(eattr)<<16
    }
}

// ---------------- output GEMM: LDS-staged f16 A, f32 out ----------------
__global__ __launch_bounds__(256) void gemm_out(const _Float16* __restrict__ Ah,
                                                const _Float16* __restrict__ Wfrag,
                                                const float* __restrict__ bo,
                                                float* __restrict__ C) {
    __shared__ _Float16 As[32 * LDSTRIDE];
    int tid = threadIdx.x;
    int wave = tid >> 6, lane = tid & 63;
    int m32 = lane & 31, quad = lane >> 5;
    int row0 = blockIdx.x * 32;

    {
        int r = tid >> 3;
        int c0 = (tid & 7) * 16;
        int gr = row0 + r;
        bool valid = gr < N_NODES;
        const v8h* src = (const v8h*)(Ah + (size_t)gr * 128 + c0);
        _Float16* dst = As + r * LDSTRIDE + c0;
        v8h z = {};
        *(v8h*)(dst) = valid ? src[0] : z;
        *(v8h*)(dst + 8) = valid ? src[1] : z;
    }
    __syncthreads();

    v8h af[8];
#pragma unroll
    for (int kt = 0; kt < 8; kt++)
        af[kt] = *(const v8h*)(As + m32 * LDSTRIDE + kt * 16 + quad * 8);

    int col = wave * 32 + m32;
    const _Float16* wf = Wfrag + 3 * 16384 + wave * 4096 + lane * 8;
    v16f acc;
#pragma unroll
    for (int r = 0; r < 16; r++) acc[r] = 0.0f;
#pragma unroll
    for (int kt = 0; kt < 8; kt++) {
        v8h bf = *(const v8h*)(wf + kt * 512);
        acc = __builtin_amdgcn_mfma_f32_32x32x16_f16(af[kt], bf, acc, 0, 0, 0);
    }
    float bias_v = bo[col];
#pragma unroll
    for (int r = 0; r < 16; r++) {
        int row = (r & 3) + 8 * (r >> 2) + 4 * quad;
        int gr = row0 + row;
        if (gr < N_NODES) C[(size_t)gr * 128 + col] = acc[r] + bias_v;
    }
}

// ---------------- fused attention: 16 lanes/node, K fp8 + V f16, 4B edge records ------
// R2 structure, K fp8 (R6: absmax 0.0098). no-max softmax (R1). Tail clamp to
// THIS node's last edge (e1-1). ep4: u16 col | f16 eattr.
__global__ __launch_bounds__(256) void fused_attn(const _Float16* __restrict__ Q,
                                                  const unsigned char* __restrict__ K8,
                                                  const _Float16* __restrict__ V,
                                                  const int* __restrict__ start,
                                                  const int* __restrict__ counts,
                                                  const unsigned int* __restrict__ ep4,
                                                  _Float16* __restrict__ Aout) {
    int t = blockIdx.x * 256 + threadIdx.x;
    int n = t >> 4;
    int sub = t & 15;
    if (n >= N_NODES) return;

    int s0 = start[n];
    int cnt = counts[n];
    int e1 = s0 + cnt;

    v8h_u q;
    q.v = *(const v8h*)(Q + (size_t)n * 128 + sub * 8);
    float qf[8];
#pragma unroll
    for (int j = 0; j < 8; j++) qf[j] = (float)q.e[j];

    const unsigned char* Kb = K8 + sub * 8;
    const _Float16* Vb = V + sub * 8;

    float l = 0.0f;
    float acc[8];
#pragma unroll
    for (int j = 0; j < 8; j++) acc[j] = 0.0f;

    int nb = (cnt + 15) >> 4;  // 16-edge super-blocks
    for (int b = 0; b < nb; b++) {
        int base = s0 + (b << 4);
        int li = base + sub;
        if (li >= e1) li = e1 - 1;
        unsigned int pv = ep4[li];

#pragma unroll
        for (int h = 0; h < 2; h++) {
            int hb = h << 3;
            if (base + hb < e1) {
                int cols[8];
                float eas[8];
#pragma unroll
                for (int u = 0; u < 8; u++) {
                    unsigned int w = (unsigned int)__shfl((int)pv, hb + u, 16);
                    cols[u] = (int)(w & 0xffffu);
                    eas[u] = (float)__builtin_bit_cast(_Float16, (unsigned short)(w >> 16));
                }
                // ---- load phase: 8x8B K + 8x16B V gathers, issued before any compute ----
                uint2 kw[8];
                v8h_u vv[8];
#pragma unroll
                for (int u = 0; u < 8; u++) {
                    kw[u] = *(const uint2*)(Kb + ((size_t)cols[u] << 7));
                    vv[u].v = *(const v8h*)(Vb + ((size_t)cols[u] << 7));
                }
                __builtin_amdgcn_sched_barrier(0);
                // ---- compute phase ----
#pragma unroll
                for (int u = 0; u < 8; u++) {
                    v2f k01 = cvt2_f8<false>(kw[u].x);
                    v2f k23 = cvt2_f8<true>(kw[u].x);
                    v2f k45 = cvt2_f8<false>(kw[u].y);
                    v2f k67 = cvt2_f8<true>(kw[u].y);
                    float dot = 0.0f;
                    dot = fmaf(qf[0], k01[0], dot);
                    dot = fmaf(qf[1], k01[1], dot);
                    dot = fmaf(qf[2], k23[0], dot);
                    dot = fmaf(qf[3], k23[1], dot);
                    dot = fmaf(qf[4], k45[0], dot);
                    dot = fmaf(qf[5], k45[1], dot);
                    dot = fmaf(qf[6], k67[0], dot);
                    dot = fmaf(qf[7], k67[1], dot);
                    dot += __shfl_xor(dot, 1);  // 2 lanes per head
                    float s = dot * 0.25f + eas[u];
                    bool valid = (base + hb + u) < e1;
                    float ex = valid ? __expf(s) : 0.0f;
                    l += ex;
#pragma unroll
                    for (int j = 0; j < 8; j++) acc[j] = fmaf(ex, (float)vv[u].e[j], acc[j]);
                }
            }
        }
    }

    float inv = 1.0f / (l + 1e-8f);
    _Float16 tmp[8];
#pragma unroll
    for (int j = 0; j < 8; j++) tmp[j] = (_Float16)(acc[j] * inv);
    *(v8h*)(Aout + (size_t)n * 128 + sub * 8) = *(v8h*)tmp;
}

extern "C" void kernel_launch(void* const* d_in, const int* in_sizes, int n_in,
                              void* d_out, int out_size, void* d_ws, size_t ws_size,
                              hipStream_t stream) {
    const float* x = (const float*)d_in[0];
    const int* ei = (const int*)d_in[1];
    const float* eattr = (const float*)d_in[2];
    const float* Wq = (const float*)d_in[3];
    const float* bq = (const float*)d_in[4];
    const float* Wk = (const float*)d_in[5];
    const float* bk = (const float*)d_in[6];
    const float* Wv = (const float*)d_in[7];
    const float* bv = (const float*)d_in[8];
    const float* Wo = (const float*)d_in[9];
    const float* bo = (const float*)d_in[10];
    float* out = (float*)d_out;

    const int* rowi = ei;
    const int* coli = ei + N_EDGES;

    // workspace carve (rec1 offset 8B-aligned by construction)
    _Float16* Qh = (_Float16*)d_ws;
    _Float16* Vh = Qh + (size_t)N_NODES * DIM;
    _Float16* Ah = Vh + (size_t)N_NODES * DIM;
    unsigned char* K8 = (unsigned char*)(Ah + (size_t)N_NODES * DIM);
    _Float16* Wfrag = (_Float16*)(K8 + (size_t)N_NODES * DIM);  // 4*16384 shorts
    int* counts = (int*)(Wfrag + 4 * 16384);
    int* start = counts + N_NODES;
    int* bh = start + N_NODES;            // 256*NB1
    int* within = bh + 256 * NB1;         // 256*NB1
    int* dt = within + 256 * NB1;         // 256 (+pad to 8B)
    unsigned long long* rec1 = (unsigned long long*)(dt + 256);  // N_EDGES u64
    unsigned int* ep4 = (unsigned int*)(rec1 + N_EDGES);

    // 1. W frag transform || L1 coarse hist
    prep_hist<<<64 + NB1, 256, 0, stream>>>(Wq, Wk, Wv, Wo, Wfrag, rowi, bh);
    // 2. QKV projection || scanA (within-digit over blocks; digit totals)
    qkv_scan<<<GBLK + 256, 256, 0, stream>>>(x, Wfrag, bq, bk, bv, Qh, K8, Vh,
                                             bh, within, dt);
    // 3. L1 coarse scatter (regular kernel; kernel boundary = coherence point)
    l1scat<<<NB1, 256, 0, stream>>>(rowi, coli, eattr, within, dt, rec1);
    // 4. L2 in-bucket sort -> ep4 + counts/start
    l2sort<<<196, 256, 0, stream>>>(rec1, dt, counts, start, ep4);
    // 5. fused gather-attention (16 lanes per node, K fp8 + V f16)
    int ablocks = (N_NODES * 16 + 255) / 256;
    fused_attn<<<ablocks, 256, 0, stream>>>(Qh, K8, Vh, start, counts, ep4, Ah);
    // 6. output projection
    gemm_out<<<GBLK, 256, 0, stream>>>(Ah, Wfrag, bo, out);
}

// Round 13
// 168.758 us; speedup vs baseline: 1.5498x; 1.0529x over previous
//
#include <hip/hip_runtime.h>
#include <math.h>

#define N_NODES 50000
#define N_EDGES 600000
#define DIM 128
#define HEADS 8
#define GBLK 1563   // (N_NODES+31)/32
#define NB1 586     // L1 sort blocks, 1024 edges each
#define L1E 1024

typedef _Float16 v8h __attribute__((ext_vector_type(8)));
typedef _Float16 v2h __attribute__((ext_vector_type(2)));
typedef float v16f __attribute__((ext_vector_type(16)));
typedef float v4f __attribute__((ext_vector_type(4)));
typedef float v2f __attribute__((ext_vector_type(2)));

union v8h_u {
    v8h v;
    v2h p[4];
    _Float16 e[8];
};

// ---------------- fp8 e4m3 helpers (gfx950 HW cvt; OCP e4m3fn) ----------------
__device__ __forceinline__ float e4m3_to_f32_sw(unsigned int b) {
    unsigned int s = b >> 7, E = (b >> 3) & 0xF, m = b & 7;
    float v = (E == 0) ? (float)m * 0.001953125f
                       : ldexpf(1.0f + (float)m * 0.125f, (int)E - 7);
    return s ? -v : v;
}

template <bool HI>
__device__ __forceinline__ v2f cvt2_f8(unsigned int w) {
#if __has_builtin(__builtin_amdgcn_cvt_pk_f32_fp8)
    return __builtin_amdgcn_cvt_pk_f32_fp8((int)w, HI);
#else
    v2f r;
    r[0] = e4m3_to_f32_sw((w >> (HI ? 16 : 0)) & 0xff);
    r[1] = e4m3_to_f32_sw((w >> (HI ? 24 : 8)) & 0xff);
    return r;
#endif
}

__device__ __forceinline__ unsigned char f32_to_e4m3(float v) {
#if __has_builtin(__builtin_amdgcn_cvt_pk_fp8_f32)
    return (unsigned char)(__builtin_amdgcn_cvt_pk_fp8_f32(v, v, 0, false) & 0xff);
#else
    float a = fabsf(v);
    unsigned char sgn = (v < 0.f) ? 0x80 : 0;
    if (!(a >= 0.0078125f)) {
        int m = (int)(a * 512.0f + 0.5f);
        if (m > 7) return sgn | 8;
        return sgn | (unsigned char)m;
    }
    if (a >= 448.0f) return sgn | 0x7e;
    int e;
    float fr = frexpf(a, &e);
    int mant = (int)(fr * 16.0f + 0.5f);
    int E = e + 6;
    if (mant == 16) { mant = 8; E++; }
    if (E >= 16) return sgn | 0x7e;
    return sgn | (unsigned char)((E << 3) | (mant - 8));
#endif
}

// ---------------- K1: W-frag transform + L1 coarse histogram (block-split) ------------
// blocks [0,64): Wfrag; blocks [64, 64+NB1): per-block LDS hist of digit (row>>8).
// Wq/Wk/Wv in 32x32x16 B-layout (for qkv GEMM); Wo in 16x16x32 B-layout (for the
// fused attn epilogue).
__global__ __launch_bounds__(256) void prep_hist(const float* __restrict__ Wq,
                                                 const float* __restrict__ Wk,
                                                 const float* __restrict__ Wv,
                                                 const float* __restrict__ Wo,
                                                 _Float16* __restrict__ Wfrag,
                                                 const int* __restrict__ rowi,
                                                 int* __restrict__ bh) {
    __shared__ int lh[256];
    if (blockIdx.x >= 64) {
        int b = blockIdx.x - 64;
        int t = threadIdx.x;
        lh[t] = 0;
        __syncthreads();
        int e0 = b * L1E + t;
#pragma unroll
        for (int k = 0; k < 4; k++) {
            int e = e0 + k * 256;
            if (e < N_EDGES) atomicAdd(lh + (rowi[e] >> 8), 1);
        }
        __syncthreads();
        bh[t * NB1 + b] = lh[t];
        return;
    }
    int i = blockIdx.x * 256 + threadIdx.x;  // < 16384
    int base = i * 4;
    int mat = i >> 12;
    int rem = i & 4095;
    int wave = rem >> 10;
    int kt = (rem >> 7) & 7;
    int lane = (rem >> 1) & 63;
    int jh = (rem & 1) * 4;
    int n, kbase;
    const float* src;
    if (mat == 3) {
        // Wo, 16x16x32 B-frag: n = wave*32 + (kt>>2)*16 + (lane&15),
        //                      k = (kt&3)*32 + (lane>>4)*8 + jh + j
        src = Wo;
        n = wave * 32 + ((kt >> 2) << 4) + (lane & 15);
        kbase = (kt & 3) * 32 + ((lane >> 4) & 3) * 8 + jh;
    } else {
        src = (mat == 0) ? Wq : (mat == 1) ? Wk : Wv;
        n = wave * 32 + (lane & 31);
        kbase = kt * 16 + (lane >> 5) * 8 + jh;
    }
    _Float16 o[4];
#pragma unroll
    for (int j = 0; j < 4; j++) o[j] = (_Float16)src[(kbase + j) * 128 + n];
    *(short4*)(Wfrag + base) = *(short4*)o;
}

// ---------------- K2: fused QKV GEMM + scanA (block-split) ----------------
// blocks [0, GBLK): QKV projection (Q,V f16; K fp8)
// blocks [GBLK, GBLK+256): per-digit exclusive scan over blocks + digit totals
#define LDSTRIDE 132
__global__ __launch_bounds__(256) void qkv_scan(const float* __restrict__ x,
                                                const _Float16* __restrict__ Wfrag,
                                                const float* __restrict__ bq,
                                                const float* __restrict__ bk,
                                                const float* __restrict__ bv,
                                                _Float16* __restrict__ Qh,
                                                unsigned char* __restrict__ K8,
                                                _Float16* __restrict__ Vh,
                                                const int* __restrict__ bh,
                                                int* __restrict__ within,
                                                int* __restrict__ dt) {
    __shared__ _Float16 As[32 * LDSTRIDE];
    __shared__ int sh[256];
    if (blockIdx.x >= GBLK) {
        int d = blockIdx.x - GBLK;  // digit 0..255
        int t = threadIdx.x;
        int carry = 0;
        for (int c = 0; c < 3; c++) {
            int j = c * 256 + t;
            int v = (j < NB1) ? bh[d * NB1 + j] : 0;
            __syncthreads();
            sh[t] = v;
            __syncthreads();
            for (int off = 1; off < 256; off <<= 1) {
                int a = sh[t];
                int b2 = (t >= off) ? sh[t - off] : 0;
                __syncthreads();
                sh[t] = a + b2;
                __syncthreads();
            }
            if (j < NB1) within[d * NB1 + j] = carry + sh[t] - v;
            carry += sh[255];
        }
        if (t == 0) dt[d] = carry;
        return;
    }
    int tid = threadIdx.x;
    int wave = tid >> 6, lane = tid & 63;
    int m32 = lane & 31, quad = lane >> 5;
    int row0 = blockIdx.x * 32;

    {
        int r = tid >> 3;
        int c0 = (tid & 7) * 16;
        int gr = row0 + r;
        bool valid = gr < N_NODES;
        const float4* src = (const float4*)(x + (size_t)gr * 128 + c0);
        _Float16* dst = As + r * LDSTRIDE + c0;
#pragma unroll
        for (int q = 0; q < 4; q++) {
            float4 v = valid ? src[q] : make_float4(0.f, 0.f, 0.f, 0.f);
            _Float16 o[4] = {(_Float16)v.x, (_Float16)v.y, (_Float16)v.z, (_Float16)v.w};
            *(short4*)(dst + q * 4) = *(short4*)o;
        }
    }
    __syncthreads();

    v8h af[8];
#pragma unroll
    for (int kt = 0; kt < 8; kt++)
        af[kt] = *(const v8h*)(As + m32 * LDSTRIDE + kt * 16 + quad * 8);

    int col = wave * 32 + m32;
#pragma unroll
    for (int mat = 0; mat < 3; mat++) {
        const _Float16* wf = Wfrag + mat * 16384 + wave * 4096 + lane * 8;
        v16f acc;
#pragma unroll
        for (int r = 0; r < 16; r++) acc[r] = 0.0f;
#pragma unroll
        for (int kt = 0; kt < 8; kt++) {
            v8h bf = *(const v8h*)(wf + kt * 512);
            acc = __builtin_amdgcn_mfma_f32_32x32x16_f16(af[kt], bf, acc, 0, 0, 0);
        }
        const float* bias = (mat == 0) ? bq : (mat == 1) ? bk : bv;
        float bias_v = bias[col];
        if (mat == 1) {
#pragma unroll
            for (int r = 0; r < 16; r++) {
                int row = (r & 3) + 8 * (r >> 2) + 4 * quad;
                int gr = row0 + row;
                if (gr < N_NODES) K8[(size_t)gr * 128 + col] = f32_to_e4m3(acc[r] + bias_v);
            }
        } else {
            _Float16* C = (mat == 0) ? Qh : Vh;
#pragma unroll
            for (int r = 0; r < 16; r++) {
                int row = (r & 3) + 8 * (r >> 2) + 4 * quad;
                int gr = row0 + row;
                if (gr < N_NODES) C[(size_t)gr * 128 + col] = (_Float16)(acc[r] + bias_v);
            }
        }
    }
}

// ---------------- K3: L1 coarse scatter (regular kernel; local dt scan) ----------
// rec1[pos] = row | col<<16 | f16(eattr)<<32. Kernel boundary (not grid.sync) is the
// cross-XCD visibility point — R11's cooperative fusion cost 80us in L2-flush/spin.
__global__ __launch_bounds__(256) void l1scat(const int* __restrict__ rowi,
                                              const int* __restrict__ coli,
                                              const float* __restrict__ eattr,
                                              const int* __restrict__ within,
                                              const int* __restrict__ dt,
                                              unsigned long long* __restrict__ rec1) {
    __shared__ int lh[256], base[256], sh[256];
    int b = blockIdx.x, t = threadIdx.x;
    // local exclusive scan of dt -> dto
    int v = dt[t];
    sh[t] = v;
    __syncthreads();
    for (int off = 1; off < 256; off <<= 1) {
        int a = sh[t];
        int b2 = (t >= off) ? sh[t - off] : 0;
        __syncthreads();
        sh[t] = a + b2;
        __syncthreads();
    }
    int dto = sh[t] - v;
    lh[t] = 0;
    base[t] = dto + within[t * NB1 + b];
    __syncthreads();
    int e0 = b * L1E + t;
#pragma unroll
    for (int k = 0; k < 4; k++) {
        int e = e0 + k * 256;
        if (e < N_EDGES) {
            int row = rowi[e];
            int d = row >> 8;
            int r = atomicAdd(lh + d, 1);
            unsigned short eb = __builtin_bit_cast(unsigned short, (_Float16)eattr[e]);
            rec1[base[d] + r] = (unsigned long long)row |
                                ((unsigned long long)(unsigned int)coli[e] << 16) |
                                ((unsigned long long)eb << 32);
        }
    }
}

// ---------------- K4: L2 in-bucket sort -> ep4 + counts/start (local dt scan) --------
__global__ __launch_bounds__(256) void l2sort(const unsigned long long* __restrict__ rec1,
                                              const int* __restrict__ dt,
                                              int* __restrict__ counts,
                                              int* __restrict__ start,
                                              unsigned int* __restrict__ ep4) {
    __shared__ int h[256], hs[256], r2[256], sh[256];
    int d = blockIdx.x, t = threadIdx.x;
    // local exclusive scan of dt -> seg = dto[d]
    int v0 = dt[t];
    sh[t] = v0;
    __syncthreads();
    for (int off = 1; off < 256; off <<= 1) {
        int a = sh[t];
        int b2 = (t >= off) ? sh[t - off] : 0;
        __syncthreads();
        sh[t] = a + b2;
        __syncthreads();
    }
    int cnt = dt[d];
    int s = sh[d] - cnt;  // dto[d]
    int e = s + cnt;
    __syncthreads();
    h[t] = 0;
    r2[t] = 0;
    __syncthreads();
    for (int i = s + t; i < e; i += 256) atomicAdd(h + (int)(rec1[i] & 255), 1);
    __syncthreads();
    int v = h[t];
    sh[t] = v;
    __syncthreads();
    for (int off = 1; off < 256; off <<= 1) {
        int a = sh[t];
        int b2 = (t >= off) ? sh[t - off] : 0;
        __syncthreads();
        sh[t] = a + b2;
        __syncthreads();
    }
    int ex = sh[t] - v;  // exclusive prefix within bucket
    hs[t] = ex;
    int node = (d << 8) | t;
    if (node < N_NODES) {
        counts[node] = v;
        start[node] = s + ex;
    }
    __syncthreads();
    for (int i = s + t; i < e; i += 256) {
        unsigned long long w = rec1[i];
        int ld = (int)(w & 255);
        int r = atomicAdd(r2 + ld, 1);
        ep4[s + hs[ld] + r] = (unsigned int)(w >> 16);  // col | f16(eattr)<<16
    }
}

// ---------------- fused attention + output projection ----------------
// Edge loop: R2 structure, K fp8 + V f16, 4B edge records (R6: absmax 0.0098).
// no-max softmax (R1). Tail clamp to THIS node's last edge (e1-1).
// Epilogue: block's 16 A-rows staged in LDS (132-stride), one barrier, then
// A(16x128) @ Wo(128x128) via mfma_f32_16x16x32_f16 -> f32 out directly.
// Grid is exactly 50000/16 = 3125 blocks: no tail, no early return (barrier-safe).
__global__ __launch_bounds__(256) void fused_attn(const _Float16* __restrict__ Q,
                                                  const unsigned char* __restrict__ K8,
                                                  const _Float16* __restrict__ V,
                                                  const int* __restrict__ start,
                                                  const int* __restrict__ counts,
                                                  const unsigned int* __restrict__ ep4,
                                                  const _Float16* __restrict__ Wfrag,
                                                  const float* __restrict__ bo,
                                                  float* __restrict__ out) {
    __shared__ _Float16 As16[16 * 132];
    int tid = threadIdx.x;
    int g = tid >> 4;
    int sub = tid & 15;
    int node_base = blockIdx.x * 16;
    int n = node_base + g;  // n < N_NODES always (3125*16 = 50000 exactly)

    int s0 = start[n];
    int cnt = counts[n];
    int e1 = s0 + cnt;

    v8h_u q;
    q.v = *(const v8h*)(Q + (size_t)n * 128 + sub * 8);
    float qf[8];
#pragma unroll
    for (int j = 0; j < 8; j++) qf[j] = (float)q.e[j];

    const unsigned char* Kb = K8 + sub * 8;
    const _Float16* Vb = V + sub * 8;

    float l = 0.0f;
    float acc[8];
#pragma unroll
    for (int j = 0; j < 8; j++) acc[j] = 0.0f;

    int nb = (cnt + 15) >> 4;  // 16-edge super-blocks (0 if cnt==0)
    for (int b = 0; b < nb; b++) {
        int base = s0 + (b << 4);
        int li = base + sub;
        if (li >= e1) li = e1 - 1;
        unsigned int pv = ep4[li];

#pragma unroll
        for (int h = 0; h < 2; h++) {
            int hb = h << 3;
            if (base + hb < e1) {
                int cols[8];
                float eas[8];
#pragma unroll
                for (int u = 0; u < 8; u++) {
                    unsigned int w = (unsigned int)__shfl((int)pv, hb + u, 16);
                    cols[u] = (int)(w & 0xffffu);
                    eas[u] = (float)__builtin_bit_cast(_Float16, (unsigned short)(w >> 16));
                }
                // ---- load phase: 8x8B K + 8x16B V gathers, issued before any compute ----
                uint2 kw[8];
                v8h_u vv[8];
#pragma unroll
                for (int u = 0; u < 8; u++) {
                    kw[u] = *(const uint2*)(Kb + ((size_t)cols[u] << 7));
                    vv[u].v = *(const v8h*)(Vb + ((size_t)cols[u] << 7));
                }
                __builtin_amdgcn_sched_barrier(0);
                // ---- compute phase ----
#pragma unroll
                for (int u = 0; u < 8; u++) {
                    v2f k01 = cvt2_f8<false>(kw[u].x);
                    v2f k23 = cvt2_f8<true>(kw[u].x);
                    v2f k45 = cvt2_f8<false>(kw[u].y);
                    v2f k67 = cvt2_f8<true>(kw[u].y);
                    float dot = 0.0f;
                    dot = fmaf(qf[0], k01[0], dot);
                    dot = fmaf(qf[1], k01[1], dot);
                    dot = fmaf(qf[2], k23[0], dot);
                    dot = fmaf(qf[3], k23[1], dot);
                    dot = fmaf(qf[4], k45[0], dot);
                    dot = fmaf(qf[5], k45[1], dot);
                    dot = fmaf(qf[6], k67[0], dot);
                    dot = fmaf(qf[7], k67[1], dot);
                    dot += __shfl_xor(dot, 1);  // 2 lanes per head
                    float s = dot * 0.25f + eas[u];
                    bool valid = (base + hb + u) < e1;
                    float ex = valid ? __expf(s) : 0.0f;
                    l += ex;
#pragma unroll
                    for (int j = 0; j < 8; j++) acc[j] = fmaf(ex, (float)vv[u].e[j], acc[j]);
                }
            }
        }
    }

    float inv = 1.0f / (l + 1e-8f);
    _Float16 tmp[8];
#pragma unroll
    for (int j = 0; j < 8; j++) tmp[j] = (_Float16)(acc[j] * inv);

    // ---- stage A-row slice in LDS (padded stride vs bank conflicts) ----
    *(v8h*)(As16 + g * 132 + sub * 8) = *(v8h*)tmp;
    __syncthreads();

    // ---- output projection: A(16x128) @ Wo + bo ----
    {
        int wave = tid >> 6, lane = tid & 63;
        int lrow = lane & 15, lk = lane >> 4;
        v8h af[4];
#pragma unroll
        for (int kk = 0; kk < 4; kk++)
            af[kk] = *(const v8h*)(As16 + lrow * 132 + kk * 32 + lk * 8);
        const _Float16* wofrag = Wfrag + 3 * 16384 + wave * 4096 + lane * 8;
#pragma unroll
        for (int c = 0; c < 2; c++) {
            v4f acc2 = {0.f, 0.f, 0.f, 0.f};
#pragma unroll
            for (int kk = 0; kk < 4; kk++) {
                v8h bf = *(const v8h*)(wofrag + (c * 4 + kk) * 512);
                acc2 = __builtin_amdgcn_mfma_f32_16x16x32_f16(af[kk], bf, acc2, 0, 0, 0);
            }
            int col = wave * 32 + c * 16 + lrow;
            float bias_v = bo[col];
#pragma unroll
            for (int r = 0; r < 4; r++) {
                int node = node_base + lk * 4 + r;
                out[(size_t)node * 128 + col] = acc2[r] + bias_v;
            }
        }
    }
}

extern "C" void kernel_launch(void* const* d_in, const int* in_sizes, int n_in,
                              void* d_out, int out_size, void* d_ws, size_t ws_size,
                              hipStream_t stream) {
    const float* x = (const float*)d_in[0];
    const int* ei = (const int*)d_in[1];
    const float* eattr = (const float*)d_in[2];
    const float* Wq = (const float*)d_in[3];
    const float* bq = (const float*)d_in[4];
    const float* Wk = (const float*)d_in[5];
    const float* bk = (const float*)d_in[6];
    const float* Wv = (const float*)d_in[7];
    const float* bv = (const float*)d_in[8];
    const float* Wo = (const float*)d_in[9];
    const float* bo = (const float*)d_in[10];
    float* out = (float*)d_out;

    const int* rowi = ei;
    const int* coli = ei + N_EDGES;

    // workspace carve (rec1 offset 8B-aligned by construction)
    _Float16* Qh = (_Float16*)d_ws;
    _Float16* Vh = Qh + (size_t)N_NODES * DIM;
    unsigned char* K8 = (unsigned char*)(Vh + (size_t)N_NODES * DIM);
    _Float16* Wfrag = (_Float16*)(K8 + (size_t)N_NODES * DIM);  // 4*16384 shorts
    int* counts = (int*)(Wfrag + 4 * 16384);
    int* start = counts + N_NODES;
    int* bh = start + N_NODES;            // 256*NB1
    int* within = bh + 256 * NB1;         // 256*NB1
    int* dt = within + 256 * NB1;         // 256 (+pad to 8B)
    unsigned long long* rec1 = (unsigned long long*)(dt + 256);  // N_EDGES u64
    unsigned int* ep4 = (unsigned int*)(rec1 + N_EDGES);

    // 1. W frag transform || L1 coarse hist
    prep_hist<<<64 + NB1, 256, 0, stream>>>(Wq, Wk, Wv, Wo, Wfrag, rowi, bh);
    // 2. QKV projection || scanA (within-digit over blocks; digit totals)
    qkv_scan<<<GBLK + 256, 256, 0, stream>>>(x, Wfrag, bq, bk, bv, Qh, K8, Vh,
                                             bh, within, dt);
    // 3. L1 coarse scatter (kernel boundary = coherence point)
    l1scat<<<NB1, 256, 0, stream>>>(rowi, coli, eattr, within, dt, rec1);
    // 4. L2 in-bucket sort -> ep4 + counts/start
    l2sort<<<196, 256, 0, stream>>>(rec1, dt, counts, start, ep4);
    // 5. fused gather-attention + output projection (writes out directly)
    fused_attn<<<N_NODES / 16, 256, 0, stream>>>(Qh, K8, Vh, start, counts, ep4,
                                                 Wfrag, bo, out);
}